// Round 5
// baseline (2027.178 us; speedup 1.0000x reference)
//
#include <hip/hip_runtime.h>
#include <hip/hip_cooperative_groups.h>
#include <stdint.h>

namespace cg = cooperative_groups;

#define N_NODES 20000
#define N_EDGES 320000
#define EMB     256
#define D_IN    300
#define KPAD0   320    // D_IN padded to multiple of 32
#define NCHUNK  1000   // scan chunks of 20 nodes
#define CHW     20
#define NTILE   625    // 32-row GEMM tiles (20000/32)
#define SPITCH  264    // LDS pair-plane row pitch in ushorts (+8 pad: 2-way banks only)

typedef __attribute__((ext_vector_type(8))) short s16x8;   // 8 bf16 (4 VGPRs)
typedef __attribute__((ext_vector_type(4))) float f32x4;

static __device__ __forceinline__ float bf2f(unsigned short u) {
    union { unsigned u; float f; } x; x.u = ((unsigned)u) << 16; return x.f;
}
static __device__ __forceinline__ unsigned short f2bf(float f) {
    union { float f; unsigned u; } x; x.f = f;
    unsigned r = x.u + 0x7fffu + ((x.u >> 16) & 1u);   // RNE
    return (unsigned short)(r >> 16);
}
// split v = hi + lo (each bf16), |err| <= 2^-18 |v|
static __device__ __forceinline__ void split_bf(float v, unsigned short& h, unsigned short& l) {
    h = f2bf(v);
    l = f2bf(v - bf2f(h));
}
static __device__ __forceinline__ void split8(const float* fv, s16x8& hi, s16x8& lo) {
#pragma unroll
    for (int j = 0; j < 8; ++j) {
        unsigned short h, l;
        split_bf(fv[j], h, l);
        hi[j] = (short)h; lo[j] = (short)l;
    }
}

static __device__ __forceinline__ void mfma3(f32x4 acc[2][4], const s16x8 ah[2],
                                             const s16x8 al[2], const s16x8 bh[4],
                                             const s16x8 bl[4]) {
#pragma unroll
    for (int mt = 0; mt < 2; ++mt)
#pragma unroll
        for (int nt = 0; nt < 4; ++nt) {
            acc[mt][nt] = __builtin_amdgcn_mfma_f32_16x16x32_bf16(ah[mt], bh[nt], acc[mt][nt], 0, 0, 0);
            acc[mt][nt] = __builtin_amdgcn_mfma_f32_16x16x32_bf16(ah[mt], bl[nt], acc[mt][nt], 0, 0, 0);
            acc[mt][nt] = __builtin_amdgcn_mfma_f32_16x16x32_bf16(al[mt], bh[nt], acc[mt][nt], 0, 0, 0);
        }
}

static __device__ __forceinline__ void loadB(const unsigned short* __restrict__ Wth,
                                             const unsigned short* __restrict__ Wtl,
                                             int Kpad, int k0, int wave, int l16,
                                             s16x8 bh[4], s16x8 bl[4]) {
#pragma unroll
    for (int nt = 0; nt < 4; ++nt) {
        int nn = wave * 64 + nt * 16 + l16;
        bh[nt] = *(const s16x8*)(Wth + (size_t)nn * Kpad + k0);
        bl[nt] = *(const s16x8*)(Wtl + (size_t)nn * Kpad + k0);
    }
}

// GEMM tile, A = pair planes in global. acc must be zeroed by caller.
static __device__ __forceinline__ void gemm_pairA_global(
    const unsigned short* __restrict__ Ah, const unsigned short* __restrict__ Al,
    int m_base, const unsigned short* __restrict__ Wth,
    const unsigned short* __restrict__ Wtl,
    int wave, int quad, int l16, f32x4 acc[2][4])
{
#pragma unroll 2
    for (int ks = 0; ks < EMB / 32; ++ks) {
        int k0 = ks * 32 + quad * 8;
        s16x8 bh[4], bl[4], ah[2], al[2];
        loadB(Wth, Wtl, EMB, k0, wave, l16, bh, bl);
#pragma unroll
        for (int mt = 0; mt < 2; ++mt) {
            int row = m_base + mt * 16 + l16;
            ah[mt] = *(const s16x8*)(Ah + (size_t)row * EMB + k0);
            al[mt] = *(const s16x8*)(Al + (size_t)row * EMB + k0);
        }
        mfma3(acc, ah, al, bh, bl);
    }
}

// GEMM tile, A = pair planes in LDS (padded pitch).
static __device__ __forceinline__ void gemm_pairA_lds(
    const unsigned short (*Sh)[SPITCH], const unsigned short (*Sl)[SPITCH],
    const unsigned short* __restrict__ Wth, const unsigned short* __restrict__ Wtl,
    int wave, int quad, int l16, f32x4 acc[2][4])
{
#pragma unroll 2
    for (int ks = 0; ks < EMB / 32; ++ks) {
        int k0 = ks * 32 + quad * 8;
        s16x8 bh[4], bl[4], ah[2], al[2];
        loadB(Wth, Wtl, EMB, k0, wave, l16, bh, bl);
#pragma unroll
        for (int mt = 0; mt < 2; ++mt) {
            int row = mt * 16 + l16;
            ah[mt] = *(const s16x8*)&Sh[row][k0];
            al[mt] = *(const s16x8*)&Sl[row][k0];
        }
        mfma3(acc, ah, al, bh, bl);
    }
}

struct GcnArgs {
    const float* x;
    const int* src;
    const int* dst;
    const float* w[6];
    const float* b[6];
    int* deg; int* cursor; int* row_off; int* csr_src;
    float* csr_norm; float* dinv;
    int* chunksum; int* chunkoff;
    unsigned short* wth[6];
    unsigned short* wtl[6];
    float* F;                // f32 node table [20000][256]
    unsigned short* Gh;      // pair node table hi
    unsigned short* Gl;      // pair node table lo
    float* out;
};

// ---------------- the whole GCN in one cooperative kernel ----------------

__global__ __launch_bounds__(256, 4) void k_gcn(GcnArgs a) {
    cg::grid_group grid = cg::this_grid();
    const int tid  = threadIdx.x, bid = blockIdx.x;
    const int nthr = gridDim.x * 256;
    const int gtid = bid * 256 + tid;
    const int lane = tid & 63, wave = tid >> 6;
    const int quad = lane >> 4, l16 = lane & 15;

    __shared__ char smem_raw[2 * 32 * SPITCH * 2];   // 33792 B
    unsigned short (*Sh)[SPITCH] = (unsigned short (*)[SPITCH])smem_raw;
    unsigned short (*Sl)[SPITCH] = (unsigned short (*)[SPITCH])(smem_raw + 32 * SPITCH * 2);
    int* ssum = (int*)smem_raw;   // scan scratch (P3 only)

    // ---- P0: zero deg/cursor + weight transpose/split ----
    for (int i = gtid; i < N_NODES; i += nthr) { a.deg[i] = 0; a.cursor[i] = 0; }
#pragma unroll
    for (int l = 0; l < 6; ++l) {
        const int K = l ? EMB : D_IN, Kp = l ? EMB : KPAD0;
        for (int idx = gtid; idx < EMB * Kp; idx += nthr) {
            int n = idx / Kp, k = idx - n * Kp;
            float v = (k < K) ? a.w[l][k * EMB + n] : 0.f;
            unsigned short h, lo;
            split_bf(v, h, lo);
            a.wth[l][idx] = h; a.wtl[l][idx] = lo;
        }
    }
    __threadfence(); grid.sync(); __threadfence();

    // ---- P1: in-degree ----
    for (int i = gtid; i < N_EDGES; i += nthr) atomicAdd(&a.deg[a.dst[i]], 1);
    __threadfence(); grid.sync(); __threadfence();

    // ---- P2: dinv + per-chunk degree sums ----
    for (int i = gtid; i < N_NODES; i += nthr)
        a.dinv[i] = rsqrtf((float)(a.deg[i] + 1));   // +1 self-loop
    for (int c = gtid; c < NCHUNK; c += nthr) {
        int s = 0, base = c * CHW;
        for (int k = 0; k < CHW; ++k) s += a.deg[base + k];
        a.chunksum[c] = s;
    }
    __threadfence(); grid.sync(); __threadfence();

    // ---- P3: block 0 exclusive-scans the 1000 chunk sums ----
    if (bid == 0) {
        int v[4], t = 0, idx0 = tid * 4;
#pragma unroll
        for (int k = 0; k < 4; ++k) {
            int i = idx0 + k;
            v[k] = (i < NCHUNK) ? a.chunksum[i] : 0;
            t += v[k];
        }
        ssum[tid] = t;
        __syncthreads();
        for (int off = 1; off < 256; off <<= 1) {
            int u = (tid >= off) ? ssum[tid - off] : 0;
            __syncthreads();
            ssum[tid] += u;
            __syncthreads();
        }
        int excl = tid ? ssum[tid - 1] : 0;
#pragma unroll
        for (int k = 0; k < 4; ++k) {
            int i = idx0 + k;
            if (i < NCHUNK) a.chunkoff[i] = excl;
            excl += v[k];
        }
        if (tid == 255) a.row_off[N_NODES] = ssum[255];
    }
    __threadfence(); grid.sync(); __threadfence();

    // ---- P4: row_off within each chunk ----
    for (int c = gtid; c < NCHUNK; c += nthr) {
        int off = a.chunkoff[c], base = c * CHW;
        for (int k = 0; k < CHW; ++k) { a.row_off[base + k] = off; off += a.deg[base + k]; }
    }
    __threadfence(); grid.sync(); __threadfence();

    // ---- P5+P6: edge scatter (CSR) + conv0 GEMM (independent work) ----
    for (int i = gtid; i < N_EDGES; i += nthr) {
        int s = a.src[i], d = a.dst[i];
        int pos = a.row_off[d] + atomicAdd(&a.cursor[d], 1);
        a.csr_src[pos]  = s;
        a.csr_norm[pos] = a.dinv[s] * a.dinv[d];
    }
    for (int t = bid; t < NTILE; t += gridDim.x) {
        int m_base = t * 32;
        f32x4 acc[2][4];
#pragma unroll
        for (int mt = 0; mt < 2; ++mt)
#pragma unroll
            for (int nt = 0; nt < 4; ++nt) acc[mt][nt] = (f32x4){0.f, 0.f, 0.f, 0.f};
#pragma unroll 2
        for (int ks = 0; ks < KPAD0 / 32; ++ks) {
            int k0 = ks * 32 + quad * 8;
            s16x8 bh[4], bl[4], ah[2], al[2];
            loadB(a.wth[0], a.wtl[0], KPAD0, k0, wave, l16, bh, bl);
#pragma unroll
            for (int mt = 0; mt < 2; ++mt) {
                int row = m_base + mt * 16 + l16;
                const float* ar = a.x + (size_t)row * D_IN;
                float fv[8];
                if (row == N_NODES - 1 && k0 + 8 > D_IN) {
#pragma unroll
                    for (int j = 0; j < 8; ++j) {
                        int kk = k0 + j;
                        fv[j] = (kk < D_IN) ? ar[kk] : 0.f;
                    }
                } else {
                    // k>=300 reads spill into next row; zero-padded Wt nullifies them
                    *(float4*)(fv)     = *(const float4*)(ar + k0);
                    *(float4*)(fv + 4) = *(const float4*)(ar + k0 + 4);
                }
                split8(fv, ah[mt], al[mt]);
            }
            mfma3(acc, ah, al, bh, bl);
        }
#pragma unroll
        for (int mt = 0; mt < 2; ++mt)
#pragma unroll
            for (int r = 0; r < 4; ++r) {
                int row = m_base + mt * 16 + quad * 4 + r;
#pragma unroll
                for (int nt = 0; nt < 4; ++nt) {
                    int col = wave * 64 + nt * 16 + l16;
                    a.F[(size_t)row * EMB + col] = acc[mt][nt][r];
                }
            }
    }
    __threadfence(); grid.sync(); __threadfence();

    // ---- conv layers: agg(F)->pair G ; gemm(G)->F ----
    for (int layer = 0; layer < 3; ++layer) {
        // agg: grid-stride wave-per-node (full TLP), gather f32 rows, write pair
        {
            const int wid = bid * 4 + wave, nwav = gridDim.x * 4;
            const int d0 = lane * 4;
            const float4* F4 = (const float4*)a.F;
            float4 bb = *(const float4*)(a.b[layer] + d0);
            const int relu = (layer < 2);
            for (int node = wid; node < N_NODES; node += nwav) {
                float dv = a.dinv[node];
                float ws = dv * dv;
                float4 sv = F4[(size_t)node * 64 + lane];
                float a0 = bb.x + ws * sv.x;
                float a1 = bb.y + ws * sv.y;
                float a2 = bb.z + ws * sv.z;
                float a3 = bb.w + ws * sv.w;
                int j = a.row_off[node], je = a.row_off[node + 1];
                for (; j + 3 < je; j += 4) {
                    int   s0 = a.csr_src[j],      s1 = a.csr_src[j + 1];
                    int   s2 = a.csr_src[j + 2],  s3 = a.csr_src[j + 3];
                    float w0 = a.csr_norm[j],     w1 = a.csr_norm[j + 1];
                    float w2 = a.csr_norm[j + 2], w3 = a.csr_norm[j + 3];
                    float4 v0 = F4[(size_t)s0 * 64 + lane];
                    float4 v1 = F4[(size_t)s1 * 64 + lane];
                    float4 v2 = F4[(size_t)s2 * 64 + lane];
                    float4 v3 = F4[(size_t)s3 * 64 + lane];
                    a0 += w0 * v0.x + w1 * v1.x + w2 * v2.x + w3 * v3.x;
                    a1 += w0 * v0.y + w1 * v1.y + w2 * v2.y + w3 * v3.y;
                    a2 += w0 * v0.z + w1 * v1.z + w2 * v2.z + w3 * v3.z;
                    a3 += w0 * v0.w + w1 * v1.w + w2 * v2.w + w3 * v3.w;
                }
                for (; j < je; ++j) {
                    int   s = a.csr_src[j];
                    float w = a.csr_norm[j];
                    float4 v = F4[(size_t)s * 64 + lane];
                    a0 += w * v.x; a1 += w * v.y; a2 += w * v.z; a3 += w * v.w;
                }
                if (relu) {
                    a0 = fmaxf(a0, 0.f); a1 = fmaxf(a1, 0.f);
                    a2 = fmaxf(a2, 0.f); a3 = fmaxf(a3, 0.f);
                }
                ushort4 oh, ol;
                split_bf(a0, oh.x, ol.x);
                split_bf(a1, oh.y, ol.y);
                split_bf(a2, oh.z, ol.z);
                split_bf(a3, oh.w, ol.w);
                size_t o = (size_t)node * EMB + d0;
                *(ushort4*)(a.Gh + o) = oh;
                *(ushort4*)(a.Gl + o) = ol;
            }
        }
        __threadfence(); grid.sync(); __threadfence();

        if (layer < 2) {
            // gemm: G pair @ W[layer+1] -> F (f32)
            for (int t = bid; t < NTILE; t += gridDim.x) {
                int m_base = t * 32;
                f32x4 acc[2][4];
#pragma unroll
                for (int mt = 0; mt < 2; ++mt)
#pragma unroll
                    for (int nt = 0; nt < 4; ++nt) acc[mt][nt] = (f32x4){0.f, 0.f, 0.f, 0.f};
                gemm_pairA_global(a.Gh, a.Gl, m_base, a.wth[layer + 1], a.wtl[layer + 1],
                                  wave, quad, l16, acc);
#pragma unroll
                for (int mt = 0; mt < 2; ++mt)
#pragma unroll
                    for (int r = 0; r < 4; ++r) {
                        int row = m_base + mt * 16 + quad * 4 + r;
#pragma unroll
                        for (int nt = 0; nt < 4; ++nt) {
                            int col = wave * 64 + nt * 16 + l16;
                            a.F[(size_t)row * EMB + col] = acc[mt][nt][r];
                        }
                    }
            }
            __threadfence(); grid.sync(); __threadfence();
        }
    }

    // ---- MLP chain per tile: G pair -> mlp1 -> LDS -> mlp2 -> LDS -> mlp3 -> out ----
    for (int t = bid; t < NTILE; t += gridDim.x) {
        int m_base = t * 32;
        f32x4 acc[2][4];

        // mlp1 (A from global pair)
#pragma unroll
        for (int mt = 0; mt < 2; ++mt)
#pragma unroll
            for (int nt = 0; nt < 4; ++nt) acc[mt][nt] = (f32x4){0.f, 0.f, 0.f, 0.f};
        gemm_pairA_global(a.Gh, a.Gl, m_base, a.wth[3], a.wtl[3], wave, quad, l16, acc);
        __syncthreads();   // previous iteration's LDS reads done
#pragma unroll
        for (int mt = 0; mt < 2; ++mt)
#pragma unroll
            for (int r = 0; r < 4; ++r) {
                int row = mt * 16 + quad * 4 + r;
#pragma unroll
                for (int nt = 0; nt < 4; ++nt) {
                    int col = wave * 64 + nt * 16 + l16;
                    float v = fmaxf(acc[mt][nt][r] + a.b[3][col], 0.f);
                    unsigned short h, lo;
                    split_bf(v, h, lo);
                    Sh[row][col] = h; Sl[row][col] = lo;
                }
            }
        __syncthreads();

        // mlp2 (A from LDS pair)
#pragma unroll
        for (int mt = 0; mt < 2; ++mt)
#pragma unroll
            for (int nt = 0; nt < 4; ++nt) acc[mt][nt] = (f32x4){0.f, 0.f, 0.f, 0.f};
        gemm_pairA_lds(Sh, Sl, a.wth[4], a.wtl[4], wave, quad, l16, acc);
        __syncthreads();
#pragma unroll
        for (int mt = 0; mt < 2; ++mt)
#pragma unroll
            for (int r = 0; r < 4; ++r) {
                int row = mt * 16 + quad * 4 + r;
#pragma unroll
                for (int nt = 0; nt < 4; ++nt) {
                    int col = wave * 64 + nt * 16 + l16;
                    float v = fmaxf(acc[mt][nt][r] + a.b[4][col], 0.f);
                    unsigned short h, lo;
                    split_bf(v, h, lo);
                    Sh[row][col] = h; Sl[row][col] = lo;
                }
            }
        __syncthreads();

        // mlp3 (A from LDS pair) -> d_out
#pragma unroll
        for (int mt = 0; mt < 2; ++mt)
#pragma unroll
            for (int nt = 0; nt < 4; ++nt) acc[mt][nt] = (f32x4){0.f, 0.f, 0.f, 0.f};
        gemm_pairA_lds(Sh, Sl, a.wth[5], a.wtl[5], wave, quad, l16, acc);
#pragma unroll
        for (int mt = 0; mt < 2; ++mt)
#pragma unroll
            for (int r = 0; r < 4; ++r) {
                int row = m_base + mt * 16 + quad * 4 + r;
#pragma unroll
                for (int nt = 0; nt < 4; ++nt) {
                    int col = wave * 64 + nt * 16 + l16;
                    a.out[(size_t)row * EMB + col] = acc[mt][nt][r] + a.b[5][col];
                }
            }
    }
}

// ---------------- launch: ONE cooperative dispatch ----------------

extern "C" void kernel_launch(void* const* d_in, const int* in_sizes, int n_in,
                              void* d_out, int out_size, void* d_ws, size_t ws_size,
                              hipStream_t stream) {
    GcnArgs args;
    args.x   = (const float*)d_in[0];
    const int* ei = (const int*)d_in[1];
    args.src = ei;
    args.dst = ei + N_EDGES;
    for (int i = 0; i < 6; ++i) {
        args.w[i] = (const float*)d_in[2 + 2 * i];
        args.b[i] = (const float*)d_in[3 + 2 * i];
    }

    char* wsp = (char*)d_ws;
    auto alloc = [&](size_t bytes) {
        char* p = wsp; wsp += (bytes + 255) & ~(size_t)255; return p;
    };
    args.deg      = (int*)alloc(N_NODES * 4);
    args.cursor   = (int*)alloc(N_NODES * 4);
    args.row_off  = (int*)alloc((N_NODES + 1) * 4);
    args.csr_src  = (int*)alloc(N_EDGES * 4);
    args.csr_norm = (float*)alloc(N_EDGES * 4);
    args.dinv     = (float*)alloc(N_NODES * 4);
    args.chunksum = (int*)alloc(NCHUNK * 4);
    args.chunkoff = (int*)alloc(NCHUNK * 4);
    args.wth[0] = (unsigned short*)alloc(EMB * KPAD0 * 2);
    args.wtl[0] = (unsigned short*)alloc(EMB * KPAD0 * 2);
    for (int i = 1; i < 6; ++i) {
        args.wth[i] = (unsigned short*)alloc(EMB * EMB * 2);
        args.wtl[i] = (unsigned short*)alloc(EMB * EMB * 2);
    }
    args.F   = (float*)alloc((size_t)N_NODES * EMB * 4);
    args.Gh  = (unsigned short*)alloc((size_t)N_NODES * EMB * 2);
    args.Gl  = (unsigned short*)alloc((size_t)N_NODES * EMB * 2);
    args.out = (float*)d_out;

    // size the cooperative grid from real occupancy (host-side queries, capture-safe)
    int nb = 0;
    (void)hipOccupancyMaxActiveBlocksPerMultiprocessor(
        &nb, reinterpret_cast<const void*>(k_gcn), 256, 0);
    if (nb < 1) nb = 1;
    if (nb > 4) nb = 4;
    int dev = 0, ncu = 0;
    (void)hipGetDevice(&dev);
    (void)hipDeviceGetAttribute(&ncu, hipDeviceAttributeMultiprocessorCount, dev);
    if (ncu <= 0) ncu = 256;
    int nblocks = nb * ncu;

    void* params[] = { (void*)&args };
    (void)hipLaunchCooperativeKernel(reinterpret_cast<const void*>(k_gcn),
                                     dim3(nblocks), dim3(256), params, 0, stream);
}

// Round 6
// 538.138 us; speedup vs baseline: 3.7670x; 3.7670x over previous
//
#include <hip/hip_runtime.h>
#include <stdint.h>

#define N_NODES 20000
#define N_EDGES 320000
#define EMB     256
#define D_IN    300
#define KPAD0   320    // D_IN padded to multiple of 32
#define SPITCH  264    // LDS pair-plane pitch (ushorts): stride 132 dw -> 2-way banks = free
#define SP0     328    // gemm0 LDS pitch (ushorts) for K=320
#define NTILE   1250   // 16-row tiles (20000/16)

typedef __attribute__((ext_vector_type(8))) short s16x8;   // 8 bf16 (4 VGPRs)
typedef __attribute__((ext_vector_type(4))) float f32x4;

static __device__ __forceinline__ float bf2f(unsigned short u) {
    union { unsigned u; float f; } x; x.u = ((unsigned)u) << 16; return x.f;
}
static __device__ __forceinline__ unsigned short f2bf(float f) {
    union { float f; unsigned u; } x; x.f = f;
    unsigned r = x.u + 0x7fffu + ((x.u >> 16) & 1u);   // RNE
    return (unsigned short)(r >> 16);
}
// split v = hi + lo (each bf16), |err| <= 2^-18 |v|
static __device__ __forceinline__ void split_bf(float v, unsigned short& h, unsigned short& l) {
    h = f2bf(v);
    l = f2bf(v - bf2f(h));
}

// ---------------- CSR build ----------------

__global__ void k_deg(const int* __restrict__ dst, int* __restrict__ deg, int e) {
    int i = blockIdx.x * 256 + threadIdx.x;
    if (i < e) atomicAdd(&deg[dst[i]], 1);
}

// single block: exclusive scan deg -> row_off, dinv = rsqrt(deg+1)
__global__ void k_scan(const int* __restrict__ deg, int* __restrict__ row_off,
                       float* __restrict__ dinv, int n) {
    __shared__ int sums[1024];
    int tid = threadIdx.x;
    const int chunk = (n + 1023) / 1024;
    int start = tid * chunk;
    int end   = start + chunk; if (end > n) end = n; if (start > n) start = n;
    int s = 0;
    for (int i = start; i < end; ++i) {
        s += deg[i];
        dinv[i] = rsqrtf((float)(deg[i] + 1));
    }
    sums[tid] = s;
    __syncthreads();
    for (int off = 1; off < 1024; off <<= 1) {
        int v = (tid >= off) ? sums[tid - off] : 0;
        __syncthreads();
        sums[tid] += v;
        __syncthreads();
    }
    int excl = (tid == 0) ? 0 : sums[tid - 1];
    for (int i = start; i < end; ++i) { row_off[i] = excl; excl += deg[i]; }
    if (tid == 1023) row_off[n] = excl;
}

__global__ void k_scatter(const int* __restrict__ src, const int* __restrict__ dst,
                          const int* __restrict__ row_off, int* __restrict__ cursor,
                          const float* __restrict__ dinv,
                          int* __restrict__ csr_src, float* __restrict__ csr_norm, int e) {
    int i = blockIdx.x * 256 + threadIdx.x;
    if (i >= e) return;
    int s = src[i], d = dst[i];
    int pos = row_off[d] + atomicAdd(&cursor[d], 1);
    csr_src[pos]  = s;
    csr_norm[pos] = dinv[s] * dinv[d];
}

// ---------------- batched weight transpose+split ----------------

struct WSplitArgs {
    const float* w[6];
    unsigned short* th[6];
    unsigned short* tl[6];
};

__global__ void k_wsplit_all(WSplitArgs a) {
#pragma unroll
    for (int l = 0; l < 6; ++l) {
        const int K = l ? EMB : D_IN, Kp = l ? EMB : KPAD0;
        const int tot = EMB * Kp;
        for (int idx = blockIdx.x * 256 + threadIdx.x; idx < tot; idx += gridDim.x * 256) {
            int n = idx / Kp, k = idx - n * Kp;
            float v = (k < K) ? a.w[l][k * EMB + n] : 0.f;
            unsigned short h, lo;
            split_bf(v, h, lo);
            a.th[l][idx] = h; a.tl[l][idx] = lo;
        }
    }
}

// ---------------- GEMM building blocks ----------------
// MFMA 16x16x32 bf16 layouts (HW-verified):
//   A: row = lane&15, k = (lane>>4)*8 + j
//   B: col = lane&15, k = (lane>>4)*8 + j   (rows of W^T)
//   C/D: col = lane&15, row = (lane>>4)*4 + reg

static __device__ __forceinline__ void loadB(const unsigned short* __restrict__ Wth,
                                             const unsigned short* __restrict__ Wtl,
                                             int Kpad, int k0, int wave, int l16,
                                             s16x8 bh[4], s16x8 bl[4]) {
#pragma unroll
    for (int nt = 0; nt < 4; ++nt) {
        int nn = wave * 64 + nt * 16 + l16;
        bh[nt] = *(const s16x8*)(Wth + (size_t)nn * Kpad + k0);
        bl[nt] = *(const s16x8*)(Wtl + (size_t)nn * Kpad + k0);
    }
}

static __device__ __forceinline__ void mfma3_1(f32x4 acc[4], s16x8 ah, s16x8 al,
                                               const s16x8 bh[4], const s16x8 bl[4]) {
#pragma unroll
    for (int nt = 0; nt < 4; ++nt) {
        acc[nt] = __builtin_amdgcn_mfma_f32_16x16x32_bf16(ah, bh[nt], acc[nt], 0, 0, 0);
        acc[nt] = __builtin_amdgcn_mfma_f32_16x16x32_bf16(ah, bl[nt], acc[nt], 0, 0, 0);
        acc[nt] = __builtin_amdgcn_mfma_f32_16x16x32_bf16(al, bh[nt], acc[nt], 0, 0, 0);
    }
}

// 16-row tile GEMM, A = pair planes in LDS (K=EMB), acc zeroed inside
static __device__ __forceinline__ void gemm_lds16(
    const unsigned short (*Sh)[SPITCH], const unsigned short (*Sl)[SPITCH],
    const unsigned short* __restrict__ Wth, const unsigned short* __restrict__ Wtl,
    int wave, int quad, int l16, f32x4 acc[4])
{
#pragma unroll
    for (int nt = 0; nt < 4; ++nt) acc[nt] = (f32x4){0.f, 0.f, 0.f, 0.f};
#pragma unroll 2
    for (int ks = 0; ks < EMB / 32; ++ks) {
        int k0 = ks * 32 + quad * 8;
        s16x8 bh[4], bl[4];
        loadB(Wth, Wtl, EMB, k0, wave, l16, bh, bl);
        s16x8 ah = *(const s16x8*)&Sh[l16][k0];
        s16x8 al = *(const s16x8*)&Sl[l16][k0];
        mfma3_1(acc, ah, al, bh, bl);
    }
}

// ---------------- conv0 GEMM: x[20000x300] @ W0 -> H f32 ----------------
// stage x tile into pre-split LDS pair planes once (no split8 in K-loop)

__global__ __launch_bounds__(256, 4) void k_gemm0(
    const float* __restrict__ x,
    const unsigned short* __restrict__ Wth, const unsigned short* __restrict__ Wtl,
    float* __restrict__ H)
{
    __shared__ unsigned short Sh[16][SP0];
    __shared__ unsigned short Sl[16][SP0];
    int tid  = threadIdx.x;
    int lane = tid & 63, wave = tid >> 6;
    int quad = lane >> 4, l16 = lane & 15;
    int m_base = blockIdx.x * 16;

    // stage + split: 16 rows x 320 (zero-pad past 300)
    for (int i = tid; i < 16 * KPAD0; i += 256) {
        int r = i / KPAD0, k = i - r * KPAD0;
        float v = (k < D_IN) ? x[(size_t)(m_base + r) * D_IN + k] : 0.f;
        unsigned short h, lo;
        split_bf(v, h, lo);
        Sh[r][k] = h; Sl[r][k] = lo;
    }
    __syncthreads();

    f32x4 acc[4];
#pragma unroll
    for (int nt = 0; nt < 4; ++nt) acc[nt] = (f32x4){0.f, 0.f, 0.f, 0.f};
#pragma unroll 2
    for (int ks = 0; ks < KPAD0 / 32; ++ks) {
        int k0 = ks * 32 + quad * 8;
        s16x8 bh[4], bl[4];
        loadB(Wth, Wtl, KPAD0, k0, wave, l16, bh, bl);
        s16x8 ah = *(const s16x8*)&Sh[l16][k0];
        s16x8 al = *(const s16x8*)&Sl[l16][k0];
        mfma3_1(acc, ah, al, bh, bl);
    }

#pragma unroll
    for (int r = 0; r < 4; ++r) {
        int row = m_base + quad * 4 + r;
#pragma unroll
        for (int nt = 0; nt < 4; ++nt) {
            int col = wave * 64 + nt * 16 + l16;
            H[(size_t)row * EMB + col] = acc[nt][r];
        }
    }
}

// ---------------- agg phase (shared): 16 nodes -> LDS pair planes ----------------
// wave handles 4 nodes serially; lane owns 4 consecutive dims; gathers f32 rows.

static __device__ __forceinline__ void agg_tile(
    unsigned short (*Sh)[SPITCH], unsigned short (*Sl)[SPITCH],
    int nb, int wave, int lane,
    const float* __restrict__ Fin,
    const int* __restrict__ row_off, const int* __restrict__ csr_src,
    const float* __restrict__ csr_norm, const float* __restrict__ dinv,
    const float* __restrict__ bagg, int relu)
{
    const float4* F4 = (const float4*)Fin;
    const int d0 = lane * 4;
    float4 bb = *(const float4*)(bagg + d0);
#pragma unroll
    for (int t = 0; t < 4; ++t) {
        int node = nb + wave * 4 + t;
        float dv = dinv[node];
        float ws = dv * dv;
        float4 sv = F4[(size_t)node * 64 + lane];
        float a0 = bb.x + ws * sv.x;
        float a1 = bb.y + ws * sv.y;
        float a2 = bb.z + ws * sv.z;
        float a3 = bb.w + ws * sv.w;
        int j = row_off[node], je = row_off[node + 1];
        for (; j + 3 < je; j += 4) {
            int   s0 = csr_src[j],      s1 = csr_src[j + 1];
            int   s2 = csr_src[j + 2],  s3 = csr_src[j + 3];
            float w0 = csr_norm[j],     w1 = csr_norm[j + 1];
            float w2 = csr_norm[j + 2], w3 = csr_norm[j + 3];
            float4 v0 = F4[(size_t)s0 * 64 + lane];
            float4 v1 = F4[(size_t)s1 * 64 + lane];
            float4 v2 = F4[(size_t)s2 * 64 + lane];
            float4 v3 = F4[(size_t)s3 * 64 + lane];
            a0 += w0 * v0.x + w1 * v1.x + w2 * v2.x + w3 * v3.x;
            a1 += w0 * v0.y + w1 * v1.y + w2 * v2.y + w3 * v3.y;
            a2 += w0 * v0.z + w1 * v1.z + w2 * v2.z + w3 * v3.z;
            a3 += w0 * v0.w + w1 * v1.w + w2 * v2.w + w3 * v3.w;
        }
        for (; j < je; ++j) {
            int   s = csr_src[j];
            float w = csr_norm[j];
            float4 v = F4[(size_t)s * 64 + lane];
            a0 += w * v.x; a1 += w * v.y; a2 += w * v.z; a3 += w * v.w;
        }
        if (relu) {
            a0 = fmaxf(a0, 0.f); a1 = fmaxf(a1, 0.f);
            a2 = fmaxf(a2, 0.f); a3 = fmaxf(a3, 0.f);
        }
        ushort4 oh, ol;
        split_bf(a0, oh.x, ol.x);
        split_bf(a1, oh.y, ol.y);
        split_bf(a2, oh.z, ol.z);
        split_bf(a3, oh.w, ol.w);
        int rr = wave * 4 + t;
        *(ushort4*)&Sh[rr][d0] = oh;
        *(ushort4*)&Sl[rr][d0] = ol;
    }
}

// ---------------- fused conv: agg(Fin)+bias,relu -> LDS pair -> @W -> Fout f32 ----------------

__global__ __launch_bounds__(256, 4) void k_conv_fused(
    const float* __restrict__ Fin,
    const int* __restrict__ row_off, const int* __restrict__ csr_src,
    const float* __restrict__ csr_norm, const float* __restrict__ dinv,
    const float* __restrict__ bagg,
    const unsigned short* __restrict__ Wth, const unsigned short* __restrict__ Wtl,
    float* __restrict__ Fout)
{
    __shared__ unsigned short Sh[16][SPITCH];
    __shared__ unsigned short Sl[16][SPITCH];
    int tid  = threadIdx.x;
    int lane = tid & 63, wave = tid >> 6;
    int quad = lane >> 4, l16 = lane & 15;
    int nb   = blockIdx.x * 16;

    agg_tile(Sh, Sl, nb, wave, lane, Fin, row_off, csr_src, csr_norm, dinv, bagg, 1);
    __syncthreads();

    f32x4 acc[4];
    gemm_lds16(Sh, Sl, Wth, Wtl, wave, quad, l16, acc);

#pragma unroll
    for (int r = 0; r < 4; ++r) {
        int row = nb + quad * 4 + r;
#pragma unroll
        for (int nt = 0; nt < 4; ++nt) {
            int col = wave * 64 + nt * 16 + l16;
            Fout[(size_t)row * EMB + col] = acc[nt][r];
        }
    }
}

// ---------------- fused tail: agg(Fin)+b2 -> mlp1 -> mlp2 -> mlp3 -> out ----------------

__global__ __launch_bounds__(256, 4) void k_mlp_fused(
    const float* __restrict__ Fin,
    const int* __restrict__ row_off, const int* __restrict__ csr_src,
    const float* __restrict__ csr_norm, const float* __restrict__ dinv,
    const float* __restrict__ bagg,
    const unsigned short* __restrict__ Wth3, const unsigned short* __restrict__ Wtl3,
    const float* __restrict__ b3,
    const unsigned short* __restrict__ Wth4, const unsigned short* __restrict__ Wtl4,
    const float* __restrict__ b4,
    const unsigned short* __restrict__ Wth5, const unsigned short* __restrict__ Wtl5,
    const float* __restrict__ b5,
    float* __restrict__ out)
{
    __shared__ unsigned short Sh[16][SPITCH];
    __shared__ unsigned short Sl[16][SPITCH];
    int tid  = threadIdx.x;
    int lane = tid & 63, wave = tid >> 6;
    int quad = lane >> 4, l16 = lane & 15;
    int nb   = blockIdx.x * 16;

    agg_tile(Sh, Sl, nb, wave, lane, Fin, row_off, csr_src, csr_norm, dinv, bagg, 0);
    __syncthreads();

    f32x4 acc[4];

    // mlp1: relu(S @ W3 + b3) -> S
    gemm_lds16(Sh, Sl, Wth3, Wtl3, wave, quad, l16, acc);
    __syncthreads();
#pragma unroll
    for (int r = 0; r < 4; ++r) {
        int row = quad * 4 + r;
#pragma unroll
        for (int nt = 0; nt < 4; ++nt) {
            int col = wave * 64 + nt * 16 + l16;
            float v = fmaxf(acc[nt][r] + b3[col], 0.f);
            unsigned short h, lo;
            split_bf(v, h, lo);
            Sh[row][col] = h; Sl[row][col] = lo;
        }
    }
    __syncthreads();

    // mlp2: relu(S @ W4 + b4) -> S
    gemm_lds16(Sh, Sl, Wth4, Wtl4, wave, quad, l16, acc);
    __syncthreads();
#pragma unroll
    for (int r = 0; r < 4; ++r) {
        int row = quad * 4 + r;
#pragma unroll
        for (int nt = 0; nt < 4; ++nt) {
            int col = wave * 64 + nt * 16 + l16;
            float v = fmaxf(acc[nt][r] + b4[col], 0.f);
            unsigned short h, lo;
            split_bf(v, h, lo);
            Sh[row][col] = h; Sl[row][col] = lo;
        }
    }
    __syncthreads();

    // mlp3: S @ W5 + b5 -> out
    gemm_lds16(Sh, Sl, Wth5, Wtl5, wave, quad, l16, acc);
#pragma unroll
    for (int r = 0; r < 4; ++r) {
        int row = nb + quad * 4 + r;
#pragma unroll
        for (int nt = 0; nt < 4; ++nt) {
            int col = wave * 64 + nt * 16 + l16;
            out[(size_t)row * EMB + col] = acc[nt][r] + b5[col];
        }
    }
}

// ---------------- launch: 1 memset + 8 dispatches ----------------

extern "C" void kernel_launch(void* const* d_in, const int* in_sizes, int n_in,
                              void* d_out, int out_size, void* d_ws, size_t ws_size,
                              hipStream_t stream) {
    const float* x  = (const float*)d_in[0];
    const int*   ei = (const int*)d_in[1];
    const int* src = ei;
    const int* dst = ei + N_EDGES;

    const float* w[6];
    const float* b[6];
    for (int i = 0; i < 6; ++i) {
        w[i] = (const float*)d_in[2 + 2 * i];
        b[i] = (const float*)d_in[3 + 2 * i];
    }

    char* wsp = (char*)d_ws;
    auto alloc = [&](size_t bytes) {
        char* p = wsp; wsp += (bytes + 255) & ~(size_t)255; return p;
    };
    int*   deg      = (int*)alloc(N_NODES * 4);
    int*   cursor   = (int*)alloc(N_NODES * 4);
    int*   row_off  = (int*)alloc((N_NODES + 1) * 4);
    int*   csr_src  = (int*)alloc(N_EDGES * 4);
    float* csr_norm = (float*)alloc(N_EDGES * 4);
    float* dinv     = (float*)alloc(N_NODES * 4);
    unsigned short* wth[6];
    unsigned short* wtl[6];
    wth[0] = (unsigned short*)alloc(EMB * KPAD0 * 2);
    wtl[0] = (unsigned short*)alloc(EMB * KPAD0 * 2);
    for (int i = 1; i < 6; ++i) {
        wth[i] = (unsigned short*)alloc(EMB * EMB * 2);
        wtl[i] = (unsigned short*)alloc(EMB * EMB * 2);
    }
    float* F  = (float*)alloc((size_t)N_NODES * EMB * 4);
    float* FB = (float*)d_out;   // d_out doubles as f32 scratch

    // zero deg + cursor in one async memset (they are adjacent in ws)
    size_t zspan = (size_t)((char*)row_off - (char*)deg);
    hipMemsetAsync(deg, 0, zspan, stream);

    const int NB_E = (N_EDGES + 255) / 256;   // 1250

    k_deg<<<NB_E, 256, 0, stream>>>(dst, deg, N_EDGES);
    k_scan<<<1, 1024, 0, stream>>>(deg, row_off, dinv, N_NODES);
    k_scatter<<<NB_E, 256, 0, stream>>>(src, dst, row_off, cursor, dinv,
                                        csr_src, csr_norm, N_EDGES);

    WSplitArgs wa;
    for (int i = 0; i < 6; ++i) { wa.w[i] = w[i]; wa.th[i] = wth[i]; wa.tl[i] = wtl[i]; }
    k_wsplit_all<<<512, 256, 0, stream>>>(wa);

    // conv0 gemm: x @ W0 -> F
    k_gemm0<<<NTILE, 256, 0, stream>>>(x, wth[0], wtl[0], F);
    // conv1: agg(F)+b0,relu -> @W1 -> FB
    k_conv_fused<<<NTILE, 256, 0, stream>>>(F, row_off, csr_src, csr_norm, dinv,
                                            b[0], wth[1], wtl[1], FB);
    // conv2: agg(FB)+b1,relu -> @W2 -> F
    k_conv_fused<<<NTILE, 256, 0, stream>>>(FB, row_off, csr_src, csr_norm, dinv,
                                            b[1], wth[2], wtl[2], F);
    // tail: agg(F)+b2 -> mlp1(relu) -> mlp2(relu) -> mlp3 -> d_out
    k_mlp_fused<<<NTILE, 256, 0, stream>>>(F, row_off, csr_src, csr_norm, dinv,
                                           b[2],
                                           wth[3], wtl[3], b[3],
                                           wth[4], wtl[4], b[4],
                                           wth[5], wtl[5], b[5],
                                           FB);
}

// Round 7
// 490.417 us; speedup vs baseline: 4.1336x; 1.0973x over previous
//
#include <hip/hip_runtime.h>
#include <hip/hip_fp16.h>
#include <stdint.h>

#define N_NODES 20000
#define N_EDGES 320000
#define EMB     256
#define D_IN    300
#define KPAD0   320    // D_IN padded to multiple of 32
#define SPITCH  264    // LDS pair-plane pitch (ushorts); b128 8-way aliasing is HW floor
#define SP0     328    // gemm0 LDS pitch (ushorts) for K=320
#define NTILE   1250   // 16-row tiles (20000/16)

typedef __attribute__((ext_vector_type(8))) short s16x8;   // 8 bf16 (4 VGPRs)
typedef __attribute__((ext_vector_type(4))) float f32x4;

static __device__ __forceinline__ float bf2f(unsigned short u) {
    union { unsigned u; float f; } x; x.u = ((unsigned)u) << 16; return x.f;
}
static __device__ __forceinline__ unsigned short f2bf(float f) {
    union { float f; unsigned u; } x; x.f = f;
    unsigned r = x.u + 0x7fffu + ((x.u >> 16) & 1u);   // RNE
    return (unsigned short)(r >> 16);
}
// split v = hi + lo (each bf16), |err| <= 2^-18 |v|
static __device__ __forceinline__ void split_bf(float v, unsigned short& h, unsigned short& l) {
    h = f2bf(v);
    l = f2bf(v - bf2f(h));
}

// ---------------- CSR build ----------------

__global__ void k_deg(const int* __restrict__ dst, int* __restrict__ deg, int e) {
    int i = blockIdx.x * 256 + threadIdx.x;
    if (i < e) atomicAdd(&deg[dst[i]], 1);
}

// single block: exclusive scan deg -> row_off, dinv = rsqrt(deg+1)
__global__ void k_scan(const int* __restrict__ deg, int* __restrict__ row_off,
                       float* __restrict__ dinv, int n) {
    __shared__ int sums[1024];
    int tid = threadIdx.x;
    const int chunk = (n + 1023) / 1024;
    int start = tid * chunk;
    int end   = start + chunk; if (end > n) end = n; if (start > n) start = n;
    int s = 0;
    for (int i = start; i < end; ++i) {
        s += deg[i];
        dinv[i] = rsqrtf((float)(deg[i] + 1));
    }
    sums[tid] = s;
    __syncthreads();
    for (int off = 1; off < 1024; off <<= 1) {
        int v = (tid >= off) ? sums[tid - off] : 0;
        __syncthreads();
        sums[tid] += v;
        __syncthreads();
    }
    int excl = (tid == 0) ? 0 : sums[tid - 1];
    for (int i = start; i < end; ++i) { row_off[i] = excl; excl += deg[i]; }
    if (tid == 1023) row_off[n] = excl;
}

__global__ void k_scatter(const int* __restrict__ src, const int* __restrict__ dst,
                          const int* __restrict__ row_off, int* __restrict__ cursor,
                          const float* __restrict__ dinv,
                          int* __restrict__ csr_src, float* __restrict__ csr_norm, int e) {
    int i = blockIdx.x * 256 + threadIdx.x;
    if (i >= e) return;
    int s = src[i], d = dst[i];
    int pos = row_off[d] + atomicAdd(&cursor[d], 1);
    csr_src[pos]  = s;
    csr_norm[pos] = dinv[s] * dinv[d];
}

// ---------------- batched weight transpose+split ----------------

struct WSplitArgs {
    const float* w[6];
    unsigned short* th[6];
    unsigned short* tl[6];
};

__global__ void k_wsplit_all(WSplitArgs a) {
#pragma unroll
    for (int l = 0; l < 6; ++l) {
        const int K = l ? EMB : D_IN, Kp = l ? EMB : KPAD0;
        const int tot = EMB * Kp;
        for (int idx = blockIdx.x * 256 + threadIdx.x; idx < tot; idx += gridDim.x * 256) {
            int n = idx / Kp, k = idx - n * Kp;
            float v = (k < K) ? a.w[l][k * EMB + n] : 0.f;
            unsigned short h, lo;
            split_bf(v, h, lo);
            a.th[l][idx] = h; a.tl[l][idx] = lo;
        }
    }
}

// ---------------- GEMM building blocks ----------------
// MFMA 16x16x32 bf16 layouts (HW-verified):
//   A: row = lane&15, k = (lane>>4)*8 + j
//   B: col = lane&15, k = (lane>>4)*8 + j   (rows of W^T)
//   C/D: col = lane&15, row = (lane>>4)*4 + reg

static __device__ __forceinline__ void loadB(const unsigned short* __restrict__ Wth,
                                             const unsigned short* __restrict__ Wtl,
                                             int Kpad, int k0, int wave, int l16,
                                             s16x8 bh[4], s16x8 bl[4]) {
#pragma unroll
    for (int nt = 0; nt < 4; ++nt) {
        int nn = wave * 64 + nt * 16 + l16;
        bh[nt] = *(const s16x8*)(Wth + (size_t)nn * Kpad + k0);
        bl[nt] = *(const s16x8*)(Wtl + (size_t)nn * Kpad + k0);
    }
}

static __device__ __forceinline__ void mfma3_1(f32x4 acc[4], s16x8 ah, s16x8 al,
                                               const s16x8 bh[4], const s16x8 bl[4]) {
#pragma unroll
    for (int nt = 0; nt < 4; ++nt) {
        acc[nt] = __builtin_amdgcn_mfma_f32_16x16x32_bf16(ah, bh[nt], acc[nt], 0, 0, 0);
        acc[nt] = __builtin_amdgcn_mfma_f32_16x16x32_bf16(ah, bl[nt], acc[nt], 0, 0, 0);
        acc[nt] = __builtin_amdgcn_mfma_f32_16x16x32_bf16(al, bh[nt], acc[nt], 0, 0, 0);
    }
}

// 16-row tile GEMM, A = pair planes in LDS (K=EMB), acc zeroed inside
static __device__ __forceinline__ void gemm_lds16(
    const unsigned short (*Sh)[SPITCH], const unsigned short (*Sl)[SPITCH],
    const unsigned short* __restrict__ Wth, const unsigned short* __restrict__ Wtl,
    int wave, int quad, int l16, f32x4 acc[4])
{
#pragma unroll
    for (int nt = 0; nt < 4; ++nt) acc[nt] = (f32x4){0.f, 0.f, 0.f, 0.f};
#pragma unroll 2
    for (int ks = 0; ks < EMB / 32; ++ks) {
        int k0 = ks * 32 + quad * 8;
        s16x8 bh[4], bl[4];
        loadB(Wth, Wtl, EMB, k0, wave, l16, bh, bl);
        s16x8 ah = *(const s16x8*)&Sh[l16][k0];
        s16x8 al = *(const s16x8*)&Sl[l16][k0];
        mfma3_1(acc, ah, al, bh, bl);
    }
}

// ---------------- conv0 GEMM: x[20000x300] @ W0 -> H (fp16) ----------------

__global__ __launch_bounds__(256, 4) void k_gemm0(
    const float* __restrict__ x,
    const unsigned short* __restrict__ Wth, const unsigned short* __restrict__ Wtl,
    __half* __restrict__ H)
{
    __shared__ unsigned short Sh[16][SP0];
    __shared__ unsigned short Sl[16][SP0];
    int tid  = threadIdx.x;
    int lane = tid & 63, wave = tid >> 6;
    int quad = lane >> 4, l16 = lane & 15;
    int m_base = blockIdx.x * 16;

    // stage + split once: 16 rows x 320 (zero-pad past 300)
    for (int i = tid; i < 16 * KPAD0; i += 256) {
        int r = i / KPAD0, k = i - r * KPAD0;
        float v = (k < D_IN) ? x[(size_t)(m_base + r) * D_IN + k] : 0.f;
        unsigned short h, lo;
        split_bf(v, h, lo);
        Sh[r][k] = h; Sl[r][k] = lo;
    }
    __syncthreads();

    f32x4 acc[4];
#pragma unroll
    for (int nt = 0; nt < 4; ++nt) acc[nt] = (f32x4){0.f, 0.f, 0.f, 0.f};
#pragma unroll 2
    for (int ks = 0; ks < KPAD0 / 32; ++ks) {
        int k0 = ks * 32 + quad * 8;
        s16x8 bh[4], bl[4];
        loadB(Wth, Wtl, KPAD0, k0, wave, l16, bh, bl);
        s16x8 ah = *(const s16x8*)&Sh[l16][k0];
        s16x8 al = *(const s16x8*)&Sl[l16][k0];
        mfma3_1(acc, ah, al, bh, bl);
    }

#pragma unroll
    for (int r = 0; r < 4; ++r) {
        int row = m_base + quad * 4 + r;
#pragma unroll
        for (int nt = 0; nt < 4; ++nt) {
            int col = wave * 64 + nt * 16 + l16;
            H[(size_t)row * EMB + col] = __float2half(acc[nt][r]);
        }
    }
}

// ---------------- agg phase: 16 nodes -> LDS pair planes ----------------
// wave handles 4 nodes serially; lane owns 4 consecutive dims.
// Gathers fp16 rows: 8B/lane, 512B/row (half the cache lines of f32).

static __device__ __forceinline__ void agg_tile(
    unsigned short (*Sh)[SPITCH], unsigned short (*Sl)[SPITCH],
    int nb, int wave, int lane,
    const __half* __restrict__ Fin,
    const int* __restrict__ row_off, const int* __restrict__ csr_src,
    const float* __restrict__ csr_norm, const float* __restrict__ dinv,
    const float* __restrict__ bagg, int relu)
{
    const int d0 = lane * 4;
    float4 bb = *(const float4*)(bagg + d0);

    auto load4 = [&](int row) -> float4 {
        uint2 u = *(const uint2*)(Fin + (size_t)row * EMB + d0);
        __half2 p0 = *(__half2*)&u.x;
        __half2 p1 = *(__half2*)&u.y;
        float2 f0 = __half22float2(p0);
        float2 f1 = __half22float2(p1);
        float4 r; r.x = f0.x; r.y = f0.y; r.z = f1.x; r.w = f1.y;
        return r;
    };

#pragma unroll
    for (int t = 0; t < 4; ++t) {
        int node = nb + wave * 4 + t;
        float dv = dinv[node];
        float ws = dv * dv;
        float4 sv = load4(node);
        float a0 = bb.x + ws * sv.x;
        float a1 = bb.y + ws * sv.y;
        float a2 = bb.z + ws * sv.z;
        float a3 = bb.w + ws * sv.w;
        int j = row_off[node], je = row_off[node + 1];
        for (; j + 3 < je; j += 4) {
            int   s0 = csr_src[j],      s1 = csr_src[j + 1];
            int   s2 = csr_src[j + 2],  s3 = csr_src[j + 3];
            float w0 = csr_norm[j],     w1 = csr_norm[j + 1];
            float w2 = csr_norm[j + 2], w3 = csr_norm[j + 3];
            float4 v0 = load4(s0);
            float4 v1 = load4(s1);
            float4 v2 = load4(s2);
            float4 v3 = load4(s3);
            a0 += w0 * v0.x + w1 * v1.x + w2 * v2.x + w3 * v3.x;
            a1 += w0 * v0.y + w1 * v1.y + w2 * v2.y + w3 * v3.y;
            a2 += w0 * v0.z + w1 * v1.z + w2 * v2.z + w3 * v3.z;
            a3 += w0 * v0.w + w1 * v1.w + w2 * v2.w + w3 * v3.w;
        }
        for (; j < je; ++j) {
            int   s = csr_src[j];
            float w = csr_norm[j];
            float4 v = load4(s);
            a0 += w * v.x; a1 += w * v.y; a2 += w * v.z; a3 += w * v.w;
        }
        if (relu) {
            a0 = fmaxf(a0, 0.f); a1 = fmaxf(a1, 0.f);
            a2 = fmaxf(a2, 0.f); a3 = fmaxf(a3, 0.f);
        }
        ushort4 oh, ol;
        split_bf(a0, oh.x, ol.x);
        split_bf(a1, oh.y, ol.y);
        split_bf(a2, oh.z, ol.z);
        split_bf(a3, oh.w, ol.w);
        int rr = wave * 4 + t;
        *(ushort4*)&Sh[rr][d0] = oh;
        *(ushort4*)&Sl[rr][d0] = ol;
    }
}

// ---------------- fused conv: agg(Fin)+bias,relu -> LDS pair -> @W -> Fout fp16 ----------------

__global__ __launch_bounds__(256, 4) void k_conv_fused(
    const __half* __restrict__ Fin,
    const int* __restrict__ row_off, const int* __restrict__ csr_src,
    const float* __restrict__ csr_norm, const float* __restrict__ dinv,
    const float* __restrict__ bagg,
    const unsigned short* __restrict__ Wth, const unsigned short* __restrict__ Wtl,
    __half* __restrict__ Fout)
{
    __shared__ unsigned short Sh[16][SPITCH];
    __shared__ unsigned short Sl[16][SPITCH];
    int tid  = threadIdx.x;
    int lane = tid & 63, wave = tid >> 6;
    int quad = lane >> 4, l16 = lane & 15;
    int nb   = blockIdx.x * 16;

    agg_tile(Sh, Sl, nb, wave, lane, Fin, row_off, csr_src, csr_norm, dinv, bagg, 1);
    __syncthreads();

    f32x4 acc[4];
    gemm_lds16(Sh, Sl, Wth, Wtl, wave, quad, l16, acc);

#pragma unroll
    for (int r = 0; r < 4; ++r) {
        int row = nb + quad * 4 + r;
#pragma unroll
        for (int nt = 0; nt < 4; ++nt) {
            int col = wave * 64 + nt * 16 + l16;
            Fout[(size_t)row * EMB + col] = __float2half(acc[nt][r]);
        }
    }
}

// ---------------- fused tail: agg(Fin)+b2 -> mlp1 -> mlp2 -> mlp3 -> out ----------------

__global__ __launch_bounds__(256, 4) void k_mlp_fused(
    const __half* __restrict__ Fin,
    const int* __restrict__ row_off, const int* __restrict__ csr_src,
    const float* __restrict__ csr_norm, const float* __restrict__ dinv,
    const float* __restrict__ bagg,
    const unsigned short* __restrict__ Wth3, const unsigned short* __restrict__ Wtl3,
    const float* __restrict__ b3,
    const unsigned short* __restrict__ Wth4, const unsigned short* __restrict__ Wtl4,
    const float* __restrict__ b4,
    const unsigned short* __restrict__ Wth5, const unsigned short* __restrict__ Wtl5,
    const float* __restrict__ b5,
    float* __restrict__ out)
{
    __shared__ unsigned short Sh[16][SPITCH];
    __shared__ unsigned short Sl[16][SPITCH];
    int tid  = threadIdx.x;
    int lane = tid & 63, wave = tid >> 6;
    int quad = lane >> 4, l16 = lane & 15;
    int nb   = blockIdx.x * 16;

    agg_tile(Sh, Sl, nb, wave, lane, Fin, row_off, csr_src, csr_norm, dinv, bagg, 0);
    __syncthreads();

    f32x4 acc[4];

    // mlp1: relu(S @ W3 + b3) -> S
    gemm_lds16(Sh, Sl, Wth3, Wtl3, wave, quad, l16, acc);
    __syncthreads();
#pragma unroll
    for (int r = 0; r < 4; ++r) {
        int row = quad * 4 + r;
#pragma unroll
        for (int nt = 0; nt < 4; ++nt) {
            int col = wave * 64 + nt * 16 + l16;
            float v = fmaxf(acc[nt][r] + b3[col], 0.f);
            unsigned short h, lo;
            split_bf(v, h, lo);
            Sh[row][col] = h; Sl[row][col] = lo;
        }
    }
    __syncthreads();

    // mlp2: relu(S @ W4 + b4) -> S
    gemm_lds16(Sh, Sl, Wth4, Wtl4, wave, quad, l16, acc);
    __syncthreads();
#pragma unroll
    for (int r = 0; r < 4; ++r) {
        int row = quad * 4 + r;
#pragma unroll
        for (int nt = 0; nt < 4; ++nt) {
            int col = wave * 64 + nt * 16 + l16;
            float v = fmaxf(acc[nt][r] + b4[col], 0.f);
            unsigned short h, lo;
            split_bf(v, h, lo);
            Sh[row][col] = h; Sl[row][col] = lo;
        }
    }
    __syncthreads();

    // mlp3: S @ W5 + b5 -> out (f32)
    gemm_lds16(Sh, Sl, Wth5, Wtl5, wave, quad, l16, acc);
#pragma unroll
    for (int r = 0; r < 4; ++r) {
        int row = nb + quad * 4 + r;
#pragma unroll
        for (int nt = 0; nt < 4; ++nt) {
            int col = wave * 64 + nt * 16 + l16;
            out[(size_t)row * EMB + col] = acc[nt][r] + b5[col];
        }
    }
}

// ---------------- launch: 1 memset + 8 dispatches ----------------

extern "C" void kernel_launch(void* const* d_in, const int* in_sizes, int n_in,
                              void* d_out, int out_size, void* d_ws, size_t ws_size,
                              hipStream_t stream) {
    const float* x  = (const float*)d_in[0];
    const int*   ei = (const int*)d_in[1];
    const int* src = ei;
    const int* dst = ei + N_EDGES;

    const float* w[6];
    const float* b[6];
    for (int i = 0; i < 6; ++i) {
        w[i] = (const float*)d_in[2 + 2 * i];
        b[i] = (const float*)d_in[3 + 2 * i];
    }

    char* wsp = (char*)d_ws;
    auto alloc = [&](size_t bytes) {
        char* p = wsp; wsp += (bytes + 255) & ~(size_t)255; return p;
    };
    int*   deg      = (int*)alloc(N_NODES * 4);
    int*   cursor   = (int*)alloc(N_NODES * 4);
    int*   row_off  = (int*)alloc((N_NODES + 1) * 4);
    int*   csr_src  = (int*)alloc(N_EDGES * 4);
    float* csr_norm = (float*)alloc(N_EDGES * 4);
    float* dinv     = (float*)alloc(N_NODES * 4);
    unsigned short* wth[6];
    unsigned short* wtl[6];
    wth[0] = (unsigned short*)alloc(EMB * KPAD0 * 2);
    wtl[0] = (unsigned short*)alloc(EMB * KPAD0 * 2);
    for (int i = 1; i < 6; ++i) {
        wth[i] = (unsigned short*)alloc(EMB * EMB * 2);
        wtl[i] = (unsigned short*)alloc(EMB * EMB * 2);
    }
    __half* FA = (__half*)alloc((size_t)N_NODES * EMB * 2);   // fp16 activation tables
    __half* FB = (__half*)alloc((size_t)N_NODES * EMB * 2);
    float*  O  = (float*)d_out;

    // zero deg + cursor in one async memset (adjacent in ws)
    size_t zspan = (size_t)((char*)row_off - (char*)deg);
    hipMemsetAsync(deg, 0, zspan, stream);

    const int NB_E = (N_EDGES + 255) / 256;   // 1250

    k_deg<<<NB_E, 256, 0, stream>>>(dst, deg, N_EDGES);
    k_scan<<<1, 1024, 0, stream>>>(deg, row_off, dinv, N_NODES);
    k_scatter<<<NB_E, 256, 0, stream>>>(src, dst, row_off, cursor, dinv,
                                        csr_src, csr_norm, N_EDGES);

    WSplitArgs wa;
    for (int i = 0; i < 6; ++i) { wa.w[i] = w[i]; wa.th[i] = wth[i]; wa.tl[i] = wtl[i]; }
    k_wsplit_all<<<512, 256, 0, stream>>>(wa);

    // conv0 gemm: x @ W0 -> FA (fp16)
    k_gemm0<<<NTILE, 256, 0, stream>>>(x, wth[0], wtl[0], FA);
    // conv1: agg(FA)+b0,relu -> @W1 -> FB
    k_conv_fused<<<NTILE, 256, 0, stream>>>(FA, row_off, csr_src, csr_norm, dinv,
                                            b[0], wth[1], wtl[1], FB);
    // conv2: agg(FB)+b1,relu -> @W2 -> FA
    k_conv_fused<<<NTILE, 256, 0, stream>>>(FB, row_off, csr_src, csr_norm, dinv,
                                            b[1], wth[2], wtl[2], FA);
    // tail: agg(FA)+b2 -> mlp1(relu) -> mlp2(relu) -> mlp3 -> d_out
    k_mlp_fused<<<NTILE, 256, 0, stream>>>(FA, row_off, csr_src, csr_norm, dinv,
                                           b[2],
                                           wth[3], wtl[3], b[3],
                                           wth[4], wtl[4], b[4],
                                           wth[5], wtl[5], b[5],
                                           O);
}